// Round 3
// baseline (1503.443 us; speedup 1.0000x reference)
//
#include <hip/hip_runtime.h>
#include <hip/hip_fp16.h>

// Problem constants
#define K_DIM   4096
#define N_DIM   11008
#define M_DIM   8192
#define NGROUPS 32            // K_DIM / 128

#define BM 128
#define BN 128
#define BK 64                 // two 16x16x32 k-steps per LDS tile

typedef __bf16 bf16x8 __attribute__((ext_vector_type(8)));
typedef float  f32x4  __attribute__((ext_vector_type(4)));

#define GAS __attribute__((address_space(1)))
#define LAS __attribute__((address_space(3)))

__device__ __forceinline__ unsigned short f2bf(float f) {
    unsigned int u = __float_as_uint(f);
    u += 0x7fffu + ((u >> 16) & 1u);   // RNE
    return (unsigned short)(u >> 16);
}

// ---- prep: x fp32 -> bf16 bits ----
__global__ void prep_x_kernel(const float4* __restrict__ x, ushort4* __restrict__ xb, int nq) {
    int stride = gridDim.x * blockDim.x;
    for (int i = blockIdx.x * blockDim.x + threadIdx.x; i < nq; i += stride) {
        float4 v = x[i];
        ushort4 o;
        o.x = f2bf(v.x); o.y = f2bf(v.y); o.z = f2bf(v.z); o.w = f2bf(v.w);
        xb[i] = o;
    }
}

// ---- prep: W dequant int32 * fp32-scale -> bf16 bits ----
// NOTE: scales were jnp.float16 in the reference but the harness only ships
// bf16/float32/int — fp16 arrives upcast to float32. Round 1/2's 6e6 absmax
// (bit-identical across staging paths) was reading them as __half.
__global__ void prep_w_kernel(const int4* __restrict__ q, const float* __restrict__ sc,
                              ushort4* __restrict__ wb, int nq) {
    int stride = gridDim.x * blockDim.x;
    for (int i = blockIdx.x * blockDim.x + threadIdx.x; i < nq; i += stride) {
        int4 v = q[i];
        int o = i >> 10;             // K_DIM/4 = 1024 quads per output row
        int g = (i & 1023) >> 5;     // 128/4 = 32 quads per group
        float s = sc[(o << 5) + g];
        ushort4 w;
        w.x = f2bf((float)v.x * s);
        w.y = f2bf((float)v.y * s);
        w.z = f2bf((float)v.z * s);
        w.w = f2bf((float)v.w * s);
        wb[i] = w;
    }
}

// ---- main GEMM: C[M,N] = A[M,K] * B[N,K]^T + bias ----
// A, B are bf16-bit ushort arrays, row-major, K contiguous.
// Staging: global_load_lds width=16 (m97 rung) — proven correct by the
// bit-identical-output experiment in rounds 1/2.
// LDS layout: tile row r holds its 8 granules of 16B at g' = g ^ (r&7)
// (XOR swizzle applied on the GLOBAL address so the wave-uniform-base
//  LDS-DMA constraint holds); fragment ds_read_b128s are 2-way/bank = free.
__global__ void gemm_bf16_kernel(const ushort* __restrict__ A, const ushort* __restrict__ B,
                                 const float* __restrict__ bias, float* __restrict__ C) {
    __shared__ __align__(16) ushort sA[BM * BK];   // 16 KB
    __shared__ __align__(16) ushort sB[BN * BK];   // 16 KB

    const int tid  = threadIdx.x;
    const int lane = tid & 63;
    const int wid  = tid >> 6;
    const int bn   = blockIdx.x;
    const int bm   = blockIdx.y;

    const ushort* Abase = A + (size_t)bm * BM * K_DIM;
    const ushort* Bbase = B + (size_t)bn * BN * K_DIM;

    // staging map: issue q covers slots [q*256, q*256+256); slot s = q*256+tid
    // -> tile row = s>>3, LDS granule g' = s&7, global granule g = g'^(row&7).
    int g_off[4];
#pragma unroll
    for (int q = 0; q < 4; ++q) {
        int slot = q * 256 + tid;
        int row  = slot >> 3;
        int g    = (slot & 7) ^ (row & 7);
        g_off[q] = row * K_DIM + g * 8;
    }
    const int lds_u = (tid & ~63) * 8;   // wave-uniform LDS element base

    f32x4 acc[4][4];
#pragma unroll
    for (int i = 0; i < 4; ++i)
#pragma unroll
        for (int j = 0; j < 4; ++j) {
            acc[i][j][0] = 0.f; acc[i][j][1] = 0.f;
            acc[i][j][2] = 0.f; acc[i][j][3] = 0.f;
        }

    const int mw = (wid & 1) * 64;
    const int nw = (wid >> 1) * 64;

    for (int kt = 0; kt < K_DIM / BK; ++kt) {
        const int kb = kt * BK;
#pragma unroll
        for (int q = 0; q < 4; ++q) {
            __builtin_amdgcn_global_load_lds(
                (GAS const void*)(Abase + kb + g_off[q]),
                (LAS void*)(&sA[q * 2048 + lds_u]), 16, 0, 0);
        }
#pragma unroll
        for (int q = 0; q < 4; ++q) {
            __builtin_amdgcn_global_load_lds(
                (GAS const void*)(Bbase + kb + g_off[q]),
                (LAS void*)(&sB[q * 2048 + lds_u]), 16, 0, 0);
        }
        __syncthreads();   // drains vmcnt(0) before barrier

#pragma unroll
        for (int ks = 0; ks < 2; ++ks) {
            bf16x8 af[4], bfr[4];
#pragma unroll
            for (int i = 0; i < 4; ++i) {
                int row = mw + i * 16 + (lane & 15);
                int g   = ks * 4 + (lane >> 4);
                int gp  = g ^ (row & 7);
                af[i] = *(const bf16x8*)&sA[row * BK + gp * 8];
            }
#pragma unroll
            for (int j = 0; j < 4; ++j) {
                int row = nw + j * 16 + (lane & 15);
                int g   = ks * 4 + (lane >> 4);
                int gp  = g ^ (row & 7);
                bfr[j] = *(const bf16x8*)&sB[row * BK + gp * 8];
            }
#pragma unroll
            for (int i = 0; i < 4; ++i)
#pragma unroll
                for (int j = 0; j < 4; ++j)
                    acc[i][j] = __builtin_amdgcn_mfma_f32_16x16x32_bf16(
                        af[i], bfr[j], acc[i][j], 0, 0, 0);
        }
        __syncthreads();
    }

    // epilogue: D layout (m89-verified): col(n) = lane&15, row(m) = (lane>>4)*4 + r
    const int col_l = lane & 15;
    const int row_l = (lane >> 4) * 4;
#pragma unroll
    for (int j = 0; j < 4; ++j) {
        int gcol = bn * BN + nw + j * 16 + col_l;
        float bv = bias[gcol];
#pragma unroll
        for (int i = 0; i < 4; ++i) {
            int grow0 = bm * BM + mw + i * 16 + row_l;
#pragma unroll
            for (int r = 0; r < 4; ++r) {
                C[(size_t)(grow0 + r) * N_DIM + gcol] = acc[i][j][r] + bv;
            }
        }
    }
}

// ---- correctness fallback if ws too small (should never run) ----
__global__ void naive_kernel(const float* __restrict__ x, const int* __restrict__ q,
                             const float* __restrict__ sc, const float* __restrict__ b,
                             float* __restrict__ out) {
    size_t idx = (size_t)blockIdx.x * blockDim.x + threadIdx.x;
    size_t total = (size_t)M_DIM * N_DIM;
    if (idx >= total) return;
    int m = (int)(idx / N_DIM);
    int n = (int)(idx % N_DIM);
    float acc = 0.f;
    for (int g = 0; g < NGROUPS; ++g) {
        float s = sc[n * NGROUPS + g];
        float p = 0.f;
        for (int k = g * 128; k < g * 128 + 128; ++k)
            p += x[(size_t)m * K_DIM + k] * (float)q[(size_t)n * K_DIM + k];
        acc += p * s;
    }
    out[idx] = acc + b[n];
}

extern "C" void kernel_launch(void* const* d_in, const int* in_sizes, int n_in,
                              void* d_out, int out_size, void* d_ws, size_t ws_size,
                              hipStream_t stream) {
    const float* x  = (const float*)d_in[0];
    const int*   wq = (const int*)d_in[1];
    const float* sc = (const float*)d_in[2];   // fp16 in reference -> fp32 from harness
    const float* bs = (const float*)d_in[3];
    float* out = (float*)d_out;

    const size_t xb_bytes = (size_t)M_DIM * K_DIM * 2;   // 67,108,864
    const size_t wb_bytes = (size_t)N_DIM * K_DIM * 2;   // 90,177,536

    if (ws_size < xb_bytes + wb_bytes) {
        // safety net: slow but correct
        size_t total = (size_t)M_DIM * N_DIM;
        int blocks = (int)((total + 255) / 256);
        naive_kernel<<<blocks, 256, 0, stream>>>(x, wq, sc, bs, out);
        return;
    }

    ushort* xb = (ushort*)d_ws;
    ushort* wb = (ushort*)((char*)d_ws + xb_bytes);

    int nq_x = M_DIM * K_DIM / 4;   // 8,388,608
    int nq_w = N_DIM * K_DIM / 4;   // 11,272,192
    prep_x_kernel<<<4096, 256, 0, stream>>>((const float4*)x, (ushort4*)xb, nq_x);
    prep_w_kernel<<<8192, 256, 0, stream>>>((const int4*)wq, sc, (ushort4*)wb, nq_w);

    dim3 grid(N_DIM / BN, M_DIM / BM);   // 86 x 64
    gemm_bf16_kernel<<<grid, 256, 0, stream>>>(xb, wb, bs, out);
}